// Round 6
// baseline (74.246 us; speedup 1.0000x reference)
//
#include <hip/hip_runtime.h>

// OHEM CrossEntropy2d: N=8, C=19, H=512, W=1024
// predict [n,c,h,w] f32, target [n,h,w] int (IGNORE=255), class_weight [19] f32
// out: scalar f32 = sum over {easy,middle,hard} of sum(w*nll)/sum(w)
//
// v5: back to the proven two-kernel v2 structure (fusion measured WORSE:
// last-block pattern +9..110us from device-scope visibility costs on
// multi-XCD gfx950). Change vs v2: PXT 8 -> 16 (4 groups of 4 px per
// thread) to double per-wave memory-level parallelism; occupancy drops
// ~8 -> ~4 waves/SIMD which a pure-streaming kernel tolerates (in-flight
// bytes still >> BW-delay product). nblocks 2048 -> 1024.

constexpr int C_CLS      = 19;
constexpr int IGNORE_LBL = 255;
constexpr int BLOCK      = 256;
constexpr int GRP        = 4;              // groups of 4 px per thread
constexpr int PXT        = 4 * GRP;        // 16 pixels per thread
constexpr int TILE       = BLOCK * PXT;    // 4096 pixels per block

typedef float f32x4 __attribute__((ext_vector_type(4)));
typedef int   i32x4 __attribute__((ext_vector_type(4)));

__global__ __launch_bounds__(BLOCK) void ohem_partial_kernel(
    const float* __restrict__ predict,
    const int*   __restrict__ target,
    const float* __restrict__ cw,
    float* __restrict__ partials,   // [6][nblocks] SoA
    int HW, int nblocks)
{
    __shared__ float s_cw[C_CLS];
    if (threadIdx.x < C_CLS) s_cw[threadIdx.x] = cw[threadIdx.x];
    __syncthreads();

    const int tile_base = blockIdx.x * TILE;          // TILE divides HW
    const int n  = tile_base / HW;
    const int hw = tile_base & (HW - 1);
    const float* base = predict + ((size_t)n * C_CLS) * (size_t)HW + hw;
    const int off0 = threadIdx.x * 4;                 // within-group offset

    int t[PXT];
    #pragma unroll
    for (int g = 0; g < GRP; ++g) {
        const i32x4 tg = __builtin_nontemporal_load(
            reinterpret_cast<const i32x4*>(target + tile_base + off0 + g * (BLOCK * 4)));
        t[g * 4 + 0] = tg.x; t[g * 4 + 1] = tg.y;
        t[g * 4 + 2] = tg.z; t[g * 4 + 3] = tg.w;
    }

    float s[PXT], lt[PXT];
    #pragma unroll
    for (int j = 0; j < PXT; ++j) { s[j] = 0.f; lt[j] = 0.f; }

    #pragma unroll
    for (int c = 0; c < C_CLS; ++c) {
        const float* p = base + (size_t)c * HW + off0;
        f32x4 v[GRP];
        #pragma unroll
        for (int g = 0; g < GRP; ++g)
            v[g] = __builtin_nontemporal_load(
                reinterpret_cast<const f32x4*>(p + g * (BLOCK * 4)));
        #pragma unroll
        for (int g = 0; g < GRP; ++g) {
            #pragma unroll
            for (int j = 0; j < 4; ++j) {
                const float va = v[g][j];
                const int   px = g * 4 + j;
                s[px]  += __expf(va);
                lt[px]  = (c == t[px]) ? va : lt[px];
            }
        }
    }

    // acc: 0=easy_w 1=easy_wnll 2=mid_w 3=mid_wnll 4=hard_w 5=hard_wnll
    float acc0 = 0.f, acc1 = 0.f, acc2 = 0.f, acc3 = 0.f, acc4 = 0.f, acc5 = 0.f;
    #pragma unroll
    for (int j = 0; j < PXT; ++j) {
        const bool valid = (t[j] != IGNORE_LBL);
        const int  tc    = valid ? t[j] : 0;
        const float wt   = valid ? s_cw[tc] : 0.f;
        const float nll  = __logf(s[j]) - lt[j];   // -log softmax(true)
        const float pt   = __expf(-nll);           // softmax prob of true class
        const float wn   = wt * nll;

        const bool easy = (pt >= 0.8f);
        const bool hard = (pt < 0.5f);
        const bool mid  = !easy && !hard;
        acc0 += easy ? wt : 0.f;  acc1 += easy ? wn : 0.f;
        acc2 += mid  ? wt : 0.f;  acc3 += mid  ? wn : 0.f;
        acc4 += hard ? wt : 0.f;  acc5 += hard ? wn : 0.f;
    }

    // wave (64-lane) shuffle reduction
    #pragma unroll
    for (int off = 32; off > 0; off >>= 1) {
        acc0 += __shfl_down(acc0, off);
        acc1 += __shfl_down(acc1, off);
        acc2 += __shfl_down(acc2, off);
        acc3 += __shfl_down(acc3, off);
        acc4 += __shfl_down(acc4, off);
        acc5 += __shfl_down(acc5, off);
    }

    __shared__ float red[BLOCK / 64][6];
    const int wave = threadIdx.x >> 6;
    const int lane = threadIdx.x & 63;
    if (lane == 0) {
        red[wave][0] = acc0; red[wave][1] = acc1; red[wave][2] = acc2;
        red[wave][3] = acc3; red[wave][4] = acc4; red[wave][5] = acc5;
    }
    __syncthreads();
    if (threadIdx.x == 0) {
        #pragma unroll
        for (int k = 0; k < 6; ++k) {
            float v = red[0][k];
            #pragma unroll
            for (int w = 1; w < BLOCK / 64; ++w) v += red[w][k];
            partials[k * nblocks + blockIdx.x] = v;
        }
    }
}

__global__ __launch_bounds__(BLOCK) void ohem_final_kernel(
    const float* __restrict__ partials, float* __restrict__ out, int nblocks)
{
    float a[6] = {0.f, 0.f, 0.f, 0.f, 0.f, 0.f};
    for (int i = threadIdx.x; i < nblocks; i += BLOCK) {
        #pragma unroll
        for (int k = 0; k < 6; ++k) a[k] += partials[k * nblocks + i];
    }
    #pragma unroll
    for (int off = 32; off > 0; off >>= 1) {
        #pragma unroll
        for (int k = 0; k < 6; ++k) a[k] += __shfl_down(a[k], off);
    }
    __shared__ float red[BLOCK / 64][6];
    const int wave = threadIdx.x >> 6;
    const int lane = threadIdx.x & 63;
    if (lane == 0) {
        #pragma unroll
        for (int k = 0; k < 6; ++k) red[wave][k] = a[k];
    }
    __syncthreads();
    if (threadIdx.x == 0) {
        float r[6];
        #pragma unroll
        for (int k = 0; k < 6; ++k)
            r[k] = red[0][k] + red[1][k] + red[2][k] + red[3][k];
        const float eps = 1e-12f;
        out[0] = r[1] / fmaxf(r[0], eps)
               + r[3] / fmaxf(r[2], eps)
               + r[5] / fmaxf(r[4], eps);
    }
}

extern "C" void kernel_launch(void* const* d_in, const int* in_sizes, int n_in,
                              void* d_out, int out_size, void* d_ws, size_t ws_size,
                              hipStream_t stream) {
    const float* predict = (const float*)d_in[0];
    const int*   target  = (const int*)d_in[1];
    const float* cw      = (const float*)d_in[2];
    float* out      = (float*)d_out;
    float* partials = (float*)d_ws;        // 6 * nblocks * 4 B

    const int HW = 512 * 1024;             // per-image plane (pow2, TILE-aligned)
    const int N  = in_sizes[1];            // 8*512*1024 pixels
    const int nblocks = N / TILE;          // 1024 for this shape

    ohem_partial_kernel<<<nblocks, BLOCK, 0, stream>>>(
        predict, target, cw, partials, HW, nblocks);
    ohem_final_kernel<<<1, BLOCK, 0, stream>>>(partials, out, nblocks);
}

// Round 7
// 58.919 us; speedup vs baseline: 1.2601x; 1.2601x over previous
//
#include <hip/hip_runtime.h>

// OHEM CrossEntropy2d: N=8, C=19, H=512, W=1024
// predict [n,c,h,w] f32, target [n,h,w] int (IGNORE=255), class_weight [19] f32
// out: scalar f32 = sum over {easy,middle,hard} of sum(w*nll)/sum(w)
//
// v6 = v2 (the measured optimum: 61.2us) + vectorized k2 partial loads.
// Ladder so far: v1 reg-tile 86.8 | v2 stream PXT=8 61.2 | v3 fused+fence 171.3
// | v4 fused relaxed-sc1 70.1 | v5 PXT=16 74.2.  Fusion loses on multi-XCD
// gfx950 (device-scope visibility + tail > 4us launch gap); PXT=16 loses to
// the occupancy cliff. k1 runs at ~95% of the 6.29 TB/s achievable read BW.

constexpr int C_CLS      = 19;
constexpr int IGNORE_LBL = 255;
constexpr int BLOCK      = 256;
constexpr int PXT        = 8;              // pixels per thread
constexpr int TILE       = BLOCK * PXT;    // 2048 pixels per block

typedef float f32x4 __attribute__((ext_vector_type(4)));
typedef int   i32x4 __attribute__((ext_vector_type(4)));

__global__ __launch_bounds__(BLOCK) void ohem_partial_kernel(
    const float* __restrict__ predict,
    const int*   __restrict__ target,
    const float* __restrict__ cw,
    float* __restrict__ partials,   // [6][nblocks] SoA
    int HW, int nblocks)
{
    __shared__ float s_cw[C_CLS];
    if (threadIdx.x < C_CLS) s_cw[threadIdx.x] = cw[threadIdx.x];
    __syncthreads();

    const int tile_base = blockIdx.x * TILE;          // TILE divides HW
    const int n  = tile_base / HW;
    const int hw = tile_base & (HW - 1);
    const float* base = predict + ((size_t)n * C_CLS) * (size_t)HW + hw;
    const int off0 = threadIdx.x * 4;                  // group 0: 4 px
    const int off1 = off0 + BLOCK * 4;                 // group 1: +1024 px

    int t[PXT];
    {
        const i32x4 ta = __builtin_nontemporal_load(
            reinterpret_cast<const i32x4*>(target + tile_base + off0));
        const i32x4 tb = __builtin_nontemporal_load(
            reinterpret_cast<const i32x4*>(target + tile_base + off1));
        t[0] = ta.x; t[1] = ta.y; t[2] = ta.z; t[3] = ta.w;
        t[4] = tb.x; t[5] = tb.y; t[6] = tb.z; t[7] = tb.w;
    }

    float s[PXT], lt[PXT];
    #pragma unroll
    for (int j = 0; j < PXT; ++j) { s[j] = 0.f; lt[j] = 0.f; }

    #pragma unroll
    for (int c = 0; c < C_CLS; ++c) {
        const float* p = base + (size_t)c * HW;
        const f32x4 a = __builtin_nontemporal_load(
            reinterpret_cast<const f32x4*>(p + off0));
        const f32x4 b = __builtin_nontemporal_load(
            reinterpret_cast<const f32x4*>(p + off1));
        #pragma unroll
        for (int j = 0; j < 4; ++j) {
            const float va = a[j];
            s[j]  += __expf(va);
            lt[j]  = (c == t[j]) ? va : lt[j];
            const float vb = b[j];
            s[j + 4] += __expf(vb);
            lt[j + 4] = (c == t[j + 4]) ? vb : lt[j + 4];
        }
    }

    // acc: 0=easy_w 1=easy_wnll 2=mid_w 3=mid_wnll 4=hard_w 5=hard_wnll
    float acc0 = 0.f, acc1 = 0.f, acc2 = 0.f, acc3 = 0.f, acc4 = 0.f, acc5 = 0.f;
    #pragma unroll
    for (int j = 0; j < PXT; ++j) {
        const bool valid = (t[j] != IGNORE_LBL);
        const int  tc    = valid ? t[j] : 0;
        const float wt   = valid ? s_cw[tc] : 0.f;
        const float nll  = __logf(s[j]) - lt[j];   // -log softmax(true)
        const float pt   = __expf(-nll);           // softmax prob of true class
        const float wn   = wt * nll;

        const bool easy = (pt >= 0.8f);
        const bool hard = (pt < 0.5f);
        const bool mid  = !easy && !hard;
        acc0 += easy ? wt : 0.f;  acc1 += easy ? wn : 0.f;
        acc2 += mid  ? wt : 0.f;  acc3 += mid  ? wn : 0.f;
        acc4 += hard ? wt : 0.f;  acc5 += hard ? wn : 0.f;
    }

    // wave (64-lane) shuffle reduction
    #pragma unroll
    for (int off = 32; off > 0; off >>= 1) {
        acc0 += __shfl_down(acc0, off);
        acc1 += __shfl_down(acc1, off);
        acc2 += __shfl_down(acc2, off);
        acc3 += __shfl_down(acc3, off);
        acc4 += __shfl_down(acc4, off);
        acc5 += __shfl_down(acc5, off);
    }

    __shared__ float red[BLOCK / 64][6];
    const int wave = threadIdx.x >> 6;
    const int lane = threadIdx.x & 63;
    if (lane == 0) {
        red[wave][0] = acc0; red[wave][1] = acc1; red[wave][2] = acc2;
        red[wave][3] = acc3; red[wave][4] = acc4; red[wave][5] = acc5;
    }
    __syncthreads();
    if (threadIdx.x == 0) {
        #pragma unroll
        for (int k = 0; k < 6; ++k) {
            float v = red[0][k];
            #pragma unroll
            for (int w = 1; w < BLOCK / 64; ++w) v += red[w][k];
            partials[k * nblocks + blockIdx.x] = v;
        }
    }
}

__global__ __launch_bounds__(BLOCK) void ohem_final_kernel(
    const float* __restrict__ partials, float* __restrict__ out, int nblocks)
{
    // nblocks = 2048; each bucket row is [nblocks] floats, read as f32x4.
    float a[6] = {0.f, 0.f, 0.f, 0.f, 0.f, 0.f};
    const int nquads = nblocks >> 2;                   // 512
    for (int q = threadIdx.x; q < nquads; q += BLOCK) {
        #pragma unroll
        for (int k = 0; k < 6; ++k) {
            const f32x4 v = *reinterpret_cast<const f32x4*>(
                partials + k * nblocks + q * 4);
            a[k] += (v[0] + v[1]) + (v[2] + v[3]);
        }
    }
    #pragma unroll
    for (int off = 32; off > 0; off >>= 1) {
        #pragma unroll
        for (int k = 0; k < 6; ++k) a[k] += __shfl_down(a[k], off);
    }
    __shared__ float red[BLOCK / 64][6];
    const int wave = threadIdx.x >> 6;
    const int lane = threadIdx.x & 63;
    if (lane == 0) {
        #pragma unroll
        for (int k = 0; k < 6; ++k) red[wave][k] = a[k];
    }
    __syncthreads();
    if (threadIdx.x == 0) {
        float r[6];
        #pragma unroll
        for (int k = 0; k < 6; ++k)
            r[k] = red[0][k] + red[1][k] + red[2][k] + red[3][k];
        const float eps = 1e-12f;
        out[0] = r[1] / fmaxf(r[0], eps)
               + r[3] / fmaxf(r[2], eps)
               + r[5] / fmaxf(r[4], eps);
    }
}

extern "C" void kernel_launch(void* const* d_in, const int* in_sizes, int n_in,
                              void* d_out, int out_size, void* d_ws, size_t ws_size,
                              hipStream_t stream) {
    const float* predict = (const float*)d_in[0];
    const int*   target  = (const int*)d_in[1];
    const float* cw      = (const float*)d_in[2];
    float* out      = (float*)d_out;
    float* partials = (float*)d_ws;        // 6 * nblocks * 4 B

    const int HW = 512 * 1024;             // per-image plane (pow2, TILE-aligned)
    const int N  = in_sizes[1];            // 8*512*1024 pixels
    const int nblocks = N / TILE;          // 2048 for this shape

    ohem_partial_kernel<<<nblocks, BLOCK, 0, stream>>>(
        predict, target, cw, partials, HW, nblocks);
    ohem_final_kernel<<<1, BLOCK, 0, stream>>>(partials, out, nblocks);
}